// Round 1
// 598.194 us; speedup vs baseline: 1.2355x; 1.2355x over previous
//
#include <hip/hip_runtime.h>

#define BN_EPS 1e-5f
#define SCAN_CHUNK 1024  // elements per scan block (256 thr x 4)
#define BM 128           // rows per MFMA-GEMM block (8 waves x 16)

typedef __attribute__((ext_vector_type(8))) short s16x8;
typedef __attribute__((ext_vector_type(4))) float f32x4;

// ---------------------------------------------------------------- ea MLP + folded Q/K biases
__global__ __launch_bounds__(128) void k_ea(
    const float* __restrict__ nt, const float* __restrict__ et,
    const float* __restrict__ mW1, const float* __restrict__ mb1,
    const float* __restrict__ m_g, const float* __restrict__ m_b,
    const float* __restrict__ m_m, const float* __restrict__ m_v,
    const float* __restrict__ mW2, const float* __restrict__ mb2,
    const float* __restrict__ qW, const float* __restrict__ qb,
    const float* __restrict__ kW, const float* __restrict__ kb,
    float* __restrict__ eaq, float* __restrict__ eak)
{
    __shared__ float merged[256];
    __shared__ float h[128];
    __shared__ float sea[128];
    const int t = threadIdx.x;
    merged[t]       = nt[t];
    merged[128 + t] = et[t];
    __syncthreads();
    float acc = mb1[t];
    for (int i = 0; i < 256; ++i) acc = fmaf(merged[i], mW1[i * 128 + t], acc);
    acc = (acc - m_m[t]) * rsqrtf(m_v[t] + BN_EPS) * m_g[t] + m_b[t];
    h[t] = acc > 0.f ? acc : 0.f;
    __syncthreads();
    float acc2 = mb2[t];
    for (int k = 0; k < 128; ++k) acc2 = fmaf(h[k], mW2[k * 128 + t], acc2);
    sea[t] = acc2;
    __syncthreads();
    float aq = qb[t], ak = kb[t];
    for (int k = 0; k < 128; ++k) {
        const float e = sea[k];
        aq = fmaf(e, qW[k * 128 + t], aq);
        ak = fmaf(e, kW[k * 128 + t], ak);
    }
    eaq[t] = aq;
    eak[t] = ak;
}

// ---------------------------------------------------------------- weight prep: W[k][j] -> transposed bf16 hi/lo planes
// Per matrix m: P + m*32768 ushorts = [hi: 16384][lo: 16384], layout Wt[j][k].
__global__ __launch_bounds__(128) void k_prep3(
    const float* __restrict__ W0, const float* __restrict__ W1,
    const float* __restrict__ W2, ushort* __restrict__ P)
{
    const int j = blockIdx.x;   // output column of W = row of Wt
    const int m = blockIdx.y;
    const int k = threadIdx.x;
    const float* W = (m == 0) ? W0 : (m == 1) ? W1 : W2;
    const float w = W[k * 128 + j];
    unsigned u = __builtin_bit_cast(unsigned, w);
    unsigned hi = (u + 0x7fffu + ((u >> 16) & 1u)) >> 16;   // RNE to bf16
    float hif = __builtin_bit_cast(float, hi << 16);
    float res = w - hif;
    unsigned lo = __builtin_bit_cast(unsigned, res) >> 16;  // trunc of residual
    ushort* base = P + (size_t)m * 32768;
    base[j * 128 + k]         = (ushort)hi;
    base[16384 + j * 128 + k] = (ushort)lo;
}

// ---------------------------------------------------------------- MFMA GEMM core (bf16x3)
// LDS sw: two planes of Wt in bf16, each [128][128] with XOR swizzle
// byte ^= (row&7)<<4  (breaks the 16-way conflict of the 256B row stride).
__device__ __forceinline__ void stage_w(const ushort* __restrict__ wpl,
                                        ushort* __restrict__ sw, int tid)
{
    const uint4* src = (const uint4*)wpl;   // 4096 uint4 = hi plane then lo plane
#pragma unroll
    for (int it = 0; it < 8; ++it) {
        const int idx = it * 512 + tid;
        const uint4 v = src[idx];
        const int plane = idx >> 11;
        const int rr = (idx >> 4) & 127;
        const int cb = (idx & 15) << 4;                       // byte offset in row
        const int byteoff = ((rr * 256 + cb) ^ ((rr & 7) << 4));
        *(uint4*)((char*)sw + plane * 32768 + byteoff) = v;
    }
}

// A-fragment k-slots and B-fragment k-slots use the SAME (group, j) -> k
// convention, so the result is invariant to the HW's internal k permutation.
__device__ __forceinline__ void mm_core(const float* __restrict__ Arow,
                                        const ushort* __restrict__ sw,
                                        int g, int r16, f32x4 acc[8])
{
#pragma unroll
    for (int ks = 0; ks < 4; ++ks) {
        const float* ap = Arow + ks * 32 + g * 8;
        const float4 a0 = *(const float4*)(ap);
        const float4 a1 = *(const float4*)(ap + 4);
        float av[8] = {a0.x, a0.y, a0.z, a0.w, a1.x, a1.y, a1.z, a1.w};
        s16x8 ahi, alo;
#pragma unroll
        for (int j = 0; j < 8; ++j) {
            const unsigned u = __builtin_bit_cast(unsigned, av[j]);
            ahi[j] = (short)(u >> 16);
            const float hif = __builtin_bit_cast(float, u & 0xffff0000u);
            const float res = av[j] - hif;
            alo[j] = (short)(__builtin_bit_cast(unsigned, res) >> 16);
        }
        const int koff = ks * 64 + g * 16;   // bytes within a Wt row
#pragma unroll
        for (int ct = 0; ct < 8; ++ct) {
            const int row = ct * 16 + r16;
            const int byteoff = ((row * 256 + koff) ^ ((row & 7) << 4));
            const s16x8 bhi = *(const s16x8*)((const char*)sw + byteoff);
            const s16x8 blo = *(const s16x8*)((const char*)sw + 32768 + byteoff);
            acc[ct] = __builtin_amdgcn_mfma_f32_16x16x32_bf16(ahi, bhi, acc[ct], 0, 0, 0);
            acc[ct] = __builtin_amdgcn_mfma_f32_16x16x32_bf16(ahi, blo, acc[ct], 0, 0, 0);
            acc[ct] = __builtin_amdgcn_mfma_f32_16x16x32_bf16(alo, bhi, acc[ct], 0, 0, 0);
        }
    }
}

// ---------------------------------------------------------------- Q/K/V via MFMA (blockIdx.y selects matrix)
__global__ __launch_bounds__(512, 4) void k_mm_qkv(
    const float* __restrict__ x, const ushort* __restrict__ planes,
    const float* __restrict__ eaq, const float* __restrict__ eak,
    const float* __restrict__ vb,
    float* __restrict__ Q, float* __restrict__ K, float* __restrict__ V, int N)
{
    __shared__ ushort sw[2 * 128 * 128];   // 64 KB
    const int tid = threadIdx.x;
    const int sel = blockIdx.y;
    stage_w(planes + (size_t)sel * 32768, sw, tid);
    __syncthreads();

    const int wave = tid >> 6, lane = tid & 63;
    const int g = lane >> 4, r16 = lane & 15;
    const int n0 = blockIdx.x * BM + wave * 16;
    int nA = n0 + r16; if (nA >= N) nA = N - 1;

    f32x4 acc[8];
#pragma unroll
    for (int ct = 0; ct < 8; ++ct) acc[ct] = (f32x4){0.f, 0.f, 0.f, 0.f};
    mm_core(x + (size_t)nA * 128, sw, g, r16, acc);

    const float* bias = (sel == 0) ? eaq : (sel == 1) ? eak : vb;
    float* O          = (sel == 0) ? Q   : (sel == 1) ? K   : V;
    const float scale = (sel == 0) ? 0.25f : 1.0f;
#pragma unroll
    for (int ct = 0; ct < 8; ++ct) {
        const int c = ct * 16 + r16;
        const float bc = bias[c];
#pragma unroll
        for (int r = 0; r < 4; ++r) {
            const int n = n0 + g * 4 + r;   // D row = (lane>>4)*4 + reg  [m89]
            if (n < N) O[(size_t)n * 128 + c] = (acc[ct][r] + bc) * scale;
        }
    }
}

// ---------------------------------------------------------------- generic MFMA GEMM with epilogue modes
// mode 0: O = acc + bias[c]
// mode 1: O = acc + addv[n][c]            (z = x@resW + aggr; no bias)
// mode 2: O = leaky_relu(bn(acc+bias[c]))
__global__ __launch_bounds__(512, 4) void k_mm_ep(
    const float* __restrict__ A, const ushort* __restrict__ wpl,
    const float* __restrict__ bias, const float* __restrict__ addv,
    const float* __restrict__ bn_m, const float* __restrict__ bn_v,
    const float* __restrict__ bn_g, const float* __restrict__ bn_b,
    float* __restrict__ O, int N, int mode)
{
    __shared__ ushort sw[2 * 128 * 128];   // 64 KB
    const int tid = threadIdx.x;
    stage_w(wpl, sw, tid);
    __syncthreads();

    const int wave = tid >> 6, lane = tid & 63;
    const int g = lane >> 4, r16 = lane & 15;
    const int n0 = blockIdx.x * BM + wave * 16;
    int nA = n0 + r16; if (nA >= N) nA = N - 1;

    f32x4 acc[8];
#pragma unroll
    for (int ct = 0; ct < 8; ++ct) acc[ct] = (f32x4){0.f, 0.f, 0.f, 0.f};
    mm_core(A + (size_t)nA * 128, sw, g, r16, acc);

#pragma unroll
    for (int ct = 0; ct < 8; ++ct) {
        const int c = ct * 16 + r16;
        float bc = 0.f, mm = 0.f, vv = 1.f, gg = 1.f, bb = 0.f;
        if (mode != 1) bc = bias[c];
        if (mode == 2) { mm = bn_m[c]; vv = bn_v[c]; gg = bn_g[c]; bb = bn_b[c]; }
        const float rs = rsqrtf(vv + BN_EPS);
#pragma unroll
        for (int r = 0; r < 4; ++r) {
            const int n = n0 + g * 4 + r;
            if (n >= N) continue;
            float u = acc[ct][r] + bc;
            if (mode == 1) u += addv[(size_t)n * 128 + c];
            if (mode == 2) {
                u = (u - mm) * rs * gg + bb;
                u = u > 0.f ? u : 0.01f * u;
            }
            O[(size_t)n * 128 + c] = u;
        }
    }
}

// ---------------------------------------------------------------- edge pass 1: ex + ssum
__global__ __launch_bounds__(256) void k_edge1(
    const int* __restrict__ ei, const float* __restrict__ Q,
    const float* __restrict__ K, float* __restrict__ ex,
    float* __restrict__ ssum, int E)
{
    const int t = blockIdx.x * 256 + threadIdx.x;   // one (edge, head) per thread
    const int e = t >> 3;
    if (e >= E) return;
    const int h = t & 7;
    const int s = ei[e];
    const int d = ei[E + e];
    const float* qp = Q + (size_t)s * 128 + h * 16;
    const float* kp = K + (size_t)d * 128 + h * 16;
    float acc = 0.f;
#pragma unroll
    for (int r = 0; r < 4; ++r) {
        const float4 a = *(const float4*)(qp + r * 4);
        const float4 b = *(const float4*)(kp + r * 4);
        acc += a.x * b.x + a.y * b.y + a.z * b.z + a.w * b.w;
    }
    const float v = __expf(acc);   // |score| small; no max-subtraction needed
    ex[(size_t)e * 8 + h] = v;
    unsafeAtomicAdd(&ssum[(size_t)s * 8 + h], v);
}

// ---------------------------------------------------------------- CSR build (dst)
__global__ __launch_bounds__(256) void k_hist(const int* __restrict__ ei,
                                              int* __restrict__ deg, int E)
{
    const int e = blockIdx.x * 256 + threadIdx.x;
    if (e < E) atomicAdd(&deg[ei[E + e]], 1);
}

__global__ __launch_bounds__(256) void k_scan_partial(const int* __restrict__ deg,
                                                      int* __restrict__ part, int N)
{
    __shared__ int sd[256];
    const int b = blockIdx.x, t = threadIdx.x;
    const int base = b * SCAN_CHUNK + t * 4;
    int s = 0;
#pragma unroll
    for (int i = 0; i < 4; ++i) { const int idx = base + i; if (idx < N) s += deg[idx]; }
    sd[t] = s; __syncthreads();
    for (int off = 128; off > 0; off >>= 1) {
        if (t < off) sd[t] += sd[t + off];
        __syncthreads();
    }
    if (t == 0) part[b] = sd[0];
}

__global__ __launch_bounds__(256) void k_scan_top(int* __restrict__ part, int nb)
{
    __shared__ int sd[256];
    const int t = threadIdx.x;
    const int orig = (t < nb) ? part[t] : 0;
    sd[t] = orig;
    __syncthreads();
    for (int off = 1; off < 256; off <<= 1) {
        const int v = (t >= off) ? sd[t - off] : 0;
        __syncthreads();
        sd[t] += v;
        __syncthreads();
    }
    if (t < nb) part[t] = sd[t] - orig;   // exclusive
}

__global__ __launch_bounds__(256) void k_scan_final(const int* __restrict__ deg,
                                                    const int* __restrict__ part,
                                                    int* __restrict__ row_start,
                                                    int* __restrict__ cursor, int N)
{
    __shared__ int ts[256];
    const int b = blockIdx.x, t = threadIdx.x;
    const int base = b * SCAN_CHUNK + t * 4;
    int v[4]; int s = 0;
#pragma unroll
    for (int i = 0; i < 4; ++i) { const int idx = base + i; v[i] = (idx < N) ? deg[idx] : 0; s += v[i]; }
    ts[t] = s; __syncthreads();
    for (int off = 1; off < 256; off <<= 1) {
        const int vv = (t >= off) ? ts[t - off] : 0;
        __syncthreads();
        ts[t] += vv;
        __syncthreads();
    }
    int run = part[b] + ((t > 0) ? ts[t - 1] : 0);
#pragma unroll
    for (int i = 0; i < 4; ++i) {
        const int idx = base + i;
        if (idx < N) { row_start[idx] = run; cursor[idx] = run; run += v[i]; }
    }
}

__global__ __launch_bounds__(256) void k_scatter(const int* __restrict__ ei,
                                                 int* __restrict__ cursor,
                                                 int* __restrict__ elist, int E)
{
    const int e = blockIdx.x * 256 + threadIdx.x;
    if (e < E) {
        const int pos = atomicAdd(&cursor[ei[E + e]], 1);
        elist[pos] = e;
    }
}

// ---------------------------------------------------------------- aggregation: 1 wave / dst node
__global__ __launch_bounds__(256) void k_aggr(
    const int* __restrict__ ei, const int* __restrict__ elist,
    const int* __restrict__ row_start, const int* __restrict__ deg,
    const float* __restrict__ V, const float* __restrict__ ex,
    const float* __restrict__ ssum, float* __restrict__ aggr, int N, int E)
{
    const int tid = threadIdx.x;
    const int n = blockIdx.x * 4 + (tid >> 6);
    if (n >= N) return;
    const int lane = tid & 63;
    const int h = lane >> 3;
    const int rs = row_start[n];
    const int dg = deg[n];
    float2 acc = make_float2(0.f, 0.f);
    for (int j = 0; j < dg; ++j) {
        const int e = elist[rs + j];
        const int s = ei[e];
        const float a = ex[(size_t)e * 8 + h] / ssum[(size_t)s * 8 + h];
        const float2 v = *(const float2*)(V + (size_t)s * 128 + lane * 2);
        acc.x = fmaf(v.x, a, acc.x);
        acc.y = fmaf(v.y, a, acc.y);
    }
    *(float2*)(aggr + (size_t)n * 128 + lane * 2) = acc;
}

// ---------------------------------------------------------------- launch
extern "C" void kernel_launch(void* const* d_in, const int* in_sizes, int n_in,
                              void* d_out, int out_size, void* d_ws, size_t ws_size,
                              hipStream_t stream)
{
    const float* x    = (const float*)d_in[0];
    const int*   ei   = (const int*)d_in[1];
    const float* nt   = (const float*)d_in[2];
    const float* et   = (const float*)d_in[3];
    const float* mW1  = (const float*)d_in[4];
    const float* mb1  = (const float*)d_in[5];
    const float* m_g  = (const float*)d_in[6];
    const float* m_b  = (const float*)d_in[7];
    const float* m_m  = (const float*)d_in[8];
    const float* m_v  = (const float*)d_in[9];
    const float* mW2  = (const float*)d_in[10];
    const float* mb2  = (const float*)d_in[11];
    const float* resW = (const float*)d_in[12];
    const float* qW   = (const float*)d_in[13];
    const float* qb   = (const float*)d_in[14];
    const float* kW   = (const float*)d_in[15];
    const float* kb   = (const float*)d_in[16];
    const float* vW   = (const float*)d_in[17];
    const float* vb   = (const float*)d_in[18];
    const float* oW1  = (const float*)d_in[19];
    const float* ob1  = (const float*)d_in[20];
    const float* o_g  = (const float*)d_in[21];
    const float* o_b  = (const float*)d_in[22];
    const float* o_m  = (const float*)d_in[23];
    const float* o_v  = (const float*)d_in[24];
    const float* oW2  = (const float*)d_in[25];
    const float* ob2  = (const float*)d_in[26];
    float* out = (float*)d_out;

    const int N = in_sizes[0] / 128;
    const int E = in_sizes[1] / 2;

    // workspace layout (floats): eaq|eak | Q | K | V | ex | ssum | [ints] deg,row_start,cursor,part,elist
    float* ws   = (float*)d_ws;
    float* eaq  = ws;
    float* eak  = ws + 128;
    float* Q    = ws + 256;
    float* K    = Q + (size_t)N * 128;
    float* V    = K + (size_t)N * 128;
    float* ex   = V + (size_t)N * 128;
    float* ssum = ex + (size_t)E * 8;
    int* deg       = (int*)(ssum + (size_t)N * 8);
    int* row_start = deg + N;
    int* cursor    = row_start + N;
    int* part      = cursor + N;
    int* elist     = part + 256;
    float* aggr = Q;          // Q dead after edge pass 1
    float* zbuf = K;          // K dead after edge pass 1
    float* tbuf = V;          // V dead after k_aggr
    // bf16 weight planes live in dead regions:
    //   qkv planes in ssum (consumed by k_mm_qkv BEFORE ssum memset)
    //   out planes in ex   (written AFTER k_aggr, when ex is dead)
    ushort* Pq = (ushort*)ssum;   // 3 * 32768 ushorts = 192 KB  (<< N*8 floats)
    ushort* Po = (ushort*)ex;     // 192 KB  (<< E*8 floats)

    const int nbm  = (N + BM - 1) / BM;
    const int nbsc = (N + SCAN_CHUNK - 1) / SCAN_CHUNK;   // scan blocks (<=256)

    // --- weight prep + ea (before memsets; Pq aliases ssum) ---
    k_prep3<<<dim3(128, 3), 128, 0, stream>>>(qW, kW, vW, Pq);
    k_ea<<<1, 128, 0, stream>>>(nt, et, mW1, mb1, m_g, m_b, m_m, m_v, mW2, mb2,
                                qW, qb, kW, kb, eaq, eak);
    k_mm_qkv<<<dim3(nbm, 3), 512, 0, stream>>>(x, Pq, eaq, eak, vb, Q, K, V, N);

    // planes consumed -> now zero ssum/deg (stream-ordered)
    hipMemsetAsync(ssum, 0, (size_t)N * 8 * sizeof(float), stream);
    hipMemsetAsync(deg, 0, (size_t)N * sizeof(int), stream);

    // CSR build (independent of Q/K/V values)
    k_hist<<<(E + 255) / 256, 256, 0, stream>>>(ei, deg, E);
    k_scan_partial<<<nbsc, 256, 0, stream>>>(deg, part, N);
    k_scan_top<<<1, 256, 0, stream>>>(part, nbsc);
    k_scan_final<<<nbsc, 256, 0, stream>>>(deg, part, row_start, cursor, N);
    k_scatter<<<(E + 255) / 256, 256, 0, stream>>>(ei, cursor, elist, E);

    k_edge1<<<(int)(((size_t)E * 8 + 255) / 256), 256, 0, stream>>>(ei, Q, K, ex, ssum, E);
    k_aggr<<<(N + 3) / 4, 256, 0, stream>>>(ei, elist, row_start, deg, V, ex, ssum, aggr, N, E);

    // --- output chain via MFMA (ex dead now; Po aliases it) ---
    k_prep3<<<dim3(128, 3), 128, 0, stream>>>(resW, oW1, oW2, Po);
    k_mm_ep<<<nbm, 512, 0, stream>>>(x, Po, nullptr, aggr,
                                     nullptr, nullptr, nullptr, nullptr,
                                     zbuf, N, 1);
    k_mm_ep<<<nbm, 512, 0, stream>>>(zbuf, Po + 32768, ob1, nullptr,
                                     o_m, o_v, o_g, o_b,
                                     tbuf, N, 2);
    k_mm_ep<<<nbm, 512, 0, stream>>>(tbuf, Po + 65536, ob2, nullptr,
                                     nullptr, nullptr, nullptr, nullptr,
                                     out, N, 0);
}

// Round 2
// 554.682 us; speedup vs baseline: 1.3325x; 1.0784x over previous
//
#include <hip/hip_runtime.h>

#define BN_EPS 1e-5f
#define SCAN_CHUNK 1024  // elements per scan block (256 thr x 4)
#define BM 128           // rows per MFMA-GEMM block (8 waves x 16)
#define ZSTRIDE 132      // f32 z-tile LDS row stride (528 B, 16B-aligned)

typedef __attribute__((ext_vector_type(8))) short s16x8;
typedef __attribute__((ext_vector_type(4))) float f32x4;

// ---------------------------------------------------------------- ea MLP + folded Q/K biases
__global__ __launch_bounds__(128) void k_ea(
    const float* __restrict__ nt, const float* __restrict__ et,
    const float* __restrict__ mW1, const float* __restrict__ mb1,
    const float* __restrict__ m_g, const float* __restrict__ m_b,
    const float* __restrict__ m_m, const float* __restrict__ m_v,
    const float* __restrict__ mW2, const float* __restrict__ mb2,
    const float* __restrict__ qW, const float* __restrict__ qb,
    const float* __restrict__ kW, const float* __restrict__ kb,
    float* __restrict__ eaq, float* __restrict__ eak)
{
    __shared__ float merged[256];
    __shared__ float h[128];
    __shared__ float sea[128];
    const int t = threadIdx.x;
    merged[t]       = nt[t];
    merged[128 + t] = et[t];
    __syncthreads();
    float acc = mb1[t];
    for (int i = 0; i < 256; ++i) acc = fmaf(merged[i], mW1[i * 128 + t], acc);
    acc = (acc - m_m[t]) * rsqrtf(m_v[t] + BN_EPS) * m_g[t] + m_b[t];
    h[t] = acc > 0.f ? acc : 0.f;
    __syncthreads();
    float acc2 = mb2[t];
    for (int k = 0; k < 128; ++k) acc2 = fmaf(h[k], mW2[k * 128 + t], acc2);
    sea[t] = acc2;
    __syncthreads();
    float aq = qb[t], ak = kb[t];
    for (int k = 0; k < 128; ++k) {
        const float e = sea[k];
        aq = fmaf(e, qW[k * 128 + t], aq);
        ak = fmaf(e, kW[k * 128 + t], ak);
    }
    eaq[t] = aq;
    eak[t] = ak;
}

// ---------------------------------------------------------------- weight prep: W[k][j] -> transposed bf16 hi/lo planes
// Per matrix m: P + m*32768 ushorts = [hi: 16384][lo: 16384], layout Wt[j][k].
__global__ __launch_bounds__(128) void k_prep3(
    const float* __restrict__ W0, const float* __restrict__ W1,
    const float* __restrict__ W2, ushort* __restrict__ P)
{
    const int j = blockIdx.x;   // output column of W = row of Wt
    const int m = blockIdx.y;
    const int k = threadIdx.x;
    const float* W = (m == 0) ? W0 : (m == 1) ? W1 : W2;
    const float w = W[k * 128 + j];
    unsigned u = __builtin_bit_cast(unsigned, w);
    unsigned hi = (u + 0x7fffu + ((u >> 16) & 1u)) >> 16;   // RNE to bf16
    float hif = __builtin_bit_cast(float, hi << 16);
    float res = w - hif;
    unsigned lo = __builtin_bit_cast(unsigned, res) >> 16;  // trunc of residual
    ushort* base = P + (size_t)m * 32768;
    base[j * 128 + k]         = (ushort)hi;
    base[16384 + j * 128 + k] = (ushort)lo;
}

// ---------------------------------------------------------------- MFMA GEMM core (bf16x3)
// LDS sw: two planes of Wt in bf16, each [128][128] with XOR swizzle
// byte ^= (row&7)<<4  (breaks the 16-way conflict of the 256B row stride).
__device__ __forceinline__ void stage_w(const ushort* __restrict__ wpl,
                                        ushort* __restrict__ sw, int tid)
{
    const uint4* src = (const uint4*)wpl;   // 4096 uint4 = hi plane then lo plane
#pragma unroll
    for (int it = 0; it < 8; ++it) {
        const int idx = it * 512 + tid;
        const uint4 v = src[idx];
        const int plane = idx >> 11;
        const int rr = (idx >> 4) & 127;
        const int cb = (idx & 15) << 4;                       // byte offset in row
        const int byteoff = ((rr * 256 + cb) ^ ((rr & 7) << 4));
        *(uint4*)((char*)sw + plane * 32768 + byteoff) = v;
    }
}

// A-fragment k-slots and B-fragment k-slots use the SAME (group, j) -> k
// convention, so the result is invariant to the HW's internal k permutation.
// Arow may point to global memory or to an LDS f32 tile (inlined; addrspace inferred).
__device__ __forceinline__ void mm_core(const float* __restrict__ Arow,
                                        const ushort* __restrict__ sw,
                                        int g, int r16, f32x4 acc[8])
{
#pragma unroll
    for (int ks = 0; ks < 4; ++ks) {
        const float* ap = Arow + ks * 32 + g * 8;
        const float4 a0 = *(const float4*)(ap);
        const float4 a1 = *(const float4*)(ap + 4);
        float av[8] = {a0.x, a0.y, a0.z, a0.w, a1.x, a1.y, a1.z, a1.w};
        s16x8 ahi, alo;
#pragma unroll
        for (int j = 0; j < 8; ++j) {
            const unsigned u = __builtin_bit_cast(unsigned, av[j]);
            ahi[j] = (short)(u >> 16);
            const float hif = __builtin_bit_cast(float, u & 0xffff0000u);
            const float res = av[j] - hif;
            alo[j] = (short)(__builtin_bit_cast(unsigned, res) >> 16);
        }
        const int koff = ks * 64 + g * 16;   // bytes within a Wt row
#pragma unroll
        for (int ct = 0; ct < 8; ++ct) {
            const int row = ct * 16 + r16;
            const int byteoff = ((row * 256 + koff) ^ ((row & 7) << 4));
            const s16x8 bhi = *(const s16x8*)((const char*)sw + byteoff);
            const s16x8 blo = *(const s16x8*)((const char*)sw + 32768 + byteoff);
            acc[ct] = __builtin_amdgcn_mfma_f32_16x16x32_bf16(ahi, bhi, acc[ct], 0, 0, 0);
            acc[ct] = __builtin_amdgcn_mfma_f32_16x16x32_bf16(ahi, blo, acc[ct], 0, 0, 0);
            acc[ct] = __builtin_amdgcn_mfma_f32_16x16x32_bf16(alo, bhi, acc[ct], 0, 0, 0);
        }
    }
}

// ---------------------------------------------------------------- Q/K/V via MFMA (blockIdx.y selects matrix)
__global__ __launch_bounds__(512, 4) void k_mm_qkv(
    const float* __restrict__ x, const ushort* __restrict__ planes,
    const float* __restrict__ eaq, const float* __restrict__ eak,
    const float* __restrict__ vb,
    float* __restrict__ Q, float* __restrict__ K, float* __restrict__ V, int N)
{
    __shared__ ushort sw[2 * 128 * 128];   // 64 KB
    const int tid = threadIdx.x;
    const int sel = blockIdx.y;
    stage_w(planes + (size_t)sel * 32768, sw, tid);
    __syncthreads();

    const int wave = tid >> 6, lane = tid & 63;
    const int g = lane >> 4, r16 = lane & 15;
    const int n0 = blockIdx.x * BM + wave * 16;
    int nA = n0 + r16; if (nA >= N) nA = N - 1;

    f32x4 acc[8];
#pragma unroll
    for (int ct = 0; ct < 8; ++ct) acc[ct] = (f32x4){0.f, 0.f, 0.f, 0.f};
    mm_core(x + (size_t)nA * 128, sw, g, r16, acc);

    const float* bias = (sel == 0) ? eaq : (sel == 1) ? eak : vb;
    float* O          = (sel == 0) ? Q   : (sel == 1) ? K   : V;
    const float scale = (sel == 0) ? 0.25f : 1.0f;
#pragma unroll
    for (int ct = 0; ct < 8; ++ct) {
        const int c = ct * 16 + r16;
        const float bc = bias[c];
#pragma unroll
        for (int r = 0; r < 4; ++r) {
            const int n = n0 + g * 4 + r;   // D row = (lane>>4)*4 + reg  [m89]
            if (n < N) O[(size_t)n * 128 + c] = (acc[ct][r] + bc) * scale;
        }
    }
}

// ---------------------------------------------------------------- fused out chain: z = x@resW + aggr;
// t = lrelu(bn(z@oW1+ob1)); out = t@oW2 + ob2.   z/t live in LDS, never touch HBM.
__global__ __launch_bounds__(512, 2) void k_out_fused(
    const float* __restrict__ x, const ushort* __restrict__ Po,
    const float* __restrict__ aggr,
    const float* __restrict__ ob1,
    const float* __restrict__ o_m, const float* __restrict__ o_v,
    const float* __restrict__ o_g, const float* __restrict__ o_b,
    const float* __restrict__ ob2,
    float* __restrict__ out, int N)
{
    __shared__ ushort sw[2 * 128 * 128];     // 64 KB   (current weight, bf16 hi/lo)
    __shared__ float  zb[128 * ZSTRIDE];     // 67.6 KB (z then t tile, f32)
    const int tid = threadIdx.x;
    const int wave = tid >> 6, lane = tid & 63;
    const int g = lane >> 4, r16 = lane & 15;
    const int n0 = blockIdx.x * BM;
    const int arow = wave * 16 + r16;               // block-relative A row
    int nA = n0 + arow; if (nA >= N) nA = N - 1;

    // ---- GEMM1: z = x @ resW + aggr ----
    stage_w(Po, sw, tid);
    __syncthreads();
    f32x4 acc[8];
#pragma unroll
    for (int ct = 0; ct < 8; ++ct) acc[ct] = (f32x4){0.f, 0.f, 0.f, 0.f};
    mm_core(x + (size_t)nA * 128, sw, g, r16, acc);
#pragma unroll
    for (int ct = 0; ct < 8; ++ct) {
        const int c = ct * 16 + r16;
#pragma unroll
        for (int r = 0; r < 4; ++r) {
            const int nrel = wave * 16 + g * 4 + r;
            const int n = n0 + nrel;
            float u = acc[ct][r];
            if (n < N) u += aggr[(size_t)n * 128 + c];
            zb[nrel * ZSTRIDE + c] = u;
        }
    }
    __syncthreads();           // zb complete; sw reads done

    // ---- GEMM2: t = lrelu(bn(z @ oW1 + ob1)) ----
    stage_w(Po + 32768, sw, tid);
    __syncthreads();
#pragma unroll
    for (int ct = 0; ct < 8; ++ct) acc[ct] = (f32x4){0.f, 0.f, 0.f, 0.f};
    mm_core(zb + arow * ZSTRIDE, sw, g, r16, acc);
    __syncthreads();           // all zb reads + sw reads done
    // write t into zb, overlap with oW2 staging
#pragma unroll
    for (int ct = 0; ct < 8; ++ct) {
        const int c = ct * 16 + r16;
        const float bc = ob1[c];
        const float rs = rsqrtf(o_v[c] + BN_EPS);
        const float mm = o_m[c], gg = o_g[c], bb = o_b[c];
#pragma unroll
        for (int r = 0; r < 4; ++r) {
            const int nrel = wave * 16 + g * 4 + r;
            float u = acc[ct][r] + bc;
            u = (u - mm) * rs * gg + bb;
            u = u > 0.f ? u : 0.01f * u;
            zb[nrel * ZSTRIDE + c] = u;
        }
    }
    stage_w(Po + 65536, sw, tid);
    __syncthreads();

    // ---- GEMM3: out = t @ oW2 + ob2 ----
#pragma unroll
    for (int ct = 0; ct < 8; ++ct) acc[ct] = (f32x4){0.f, 0.f, 0.f, 0.f};
    mm_core(zb + arow * ZSTRIDE, sw, g, r16, acc);
#pragma unroll
    for (int ct = 0; ct < 8; ++ct) {
        const int c = ct * 16 + r16;
        const float bc = ob2[c];
#pragma unroll
        for (int r = 0; r < 4; ++r) {
            const int n = n0 + wave * 16 + g * 4 + r;
            if (n < N) out[(size_t)n * 128 + c] = acc[ct][r] + bc;
        }
    }
}

// ---------------------------------------------------------------- edge pass 1: ex (CSR-permuted) + ssum
__global__ __launch_bounds__(256) void k_edge1(
    const int* __restrict__ ei, const float* __restrict__ Q,
    const float* __restrict__ K, const int* __restrict__ epos,
    float* __restrict__ exp_, float* __restrict__ ssum, int E)
{
    const int t = blockIdx.x * 256 + threadIdx.x;   // one (edge, head) per thread
    const int e = t >> 3;
    if (e >= E) return;
    const int h = t & 7;
    const int s = ei[e];
    const int d = ei[E + e];
    const float* qp = Q + (size_t)s * 128 + h * 16;
    const float* kp = K + (size_t)d * 128 + h * 16;
    float acc = 0.f;
#pragma unroll
    for (int r = 0; r < 4; ++r) {
        const float4 a = *(const float4*)(qp + r * 4);
        const float4 b = *(const float4*)(kp + r * 4);
        acc += a.x * b.x + a.y * b.y + a.z * b.z + a.w * b.w;
    }
    const float v = __expf(acc);   // |score| small; no max-subtraction needed
    exp_[(size_t)epos[e] * 8 + h] = v;              // CSR order
    unsafeAtomicAdd(&ssum[(size_t)s * 8 + h], v);
}

// ---------------------------------------------------------------- V[s,h,:] *= 1/ssum[s,h]  (in place)
__global__ __launch_bounds__(256) void k_vscale(
    float* __restrict__ V, const float* __restrict__ ssum, int N)
{
    const int i = blockIdx.x * 256 + threadIdx.x;   // float4 index
    if (i >= N * 32) return;
    const int row = i >> 5, q = i & 31, h = q >> 2;
    const float r = 1.0f / ssum[(size_t)row * 8 + h];
    float4 v = *(float4*)(V + (size_t)i * 4);
    v.x *= r; v.y *= r; v.z *= r; v.w *= r;
    *(float4*)(V + (size_t)i * 4) = v;
}

// ---------------------------------------------------------------- CSR build (dst)
__global__ __launch_bounds__(256) void k_hist(const int* __restrict__ ei,
                                              int* __restrict__ deg, int E)
{
    const int e = blockIdx.x * 256 + threadIdx.x;
    if (e < E) atomicAdd(&deg[ei[E + e]], 1);
}

__global__ __launch_bounds__(256) void k_scan_partial(const int* __restrict__ deg,
                                                      int* __restrict__ part, int N)
{
    __shared__ int sd[256];
    const int b = blockIdx.x, t = threadIdx.x;
    const int base = b * SCAN_CHUNK + t * 4;
    int s = 0;
#pragma unroll
    for (int i = 0; i < 4; ++i) { const int idx = base + i; if (idx < N) s += deg[idx]; }
    sd[t] = s; __syncthreads();
    for (int off = 128; off > 0; off >>= 1) {
        if (t < off) sd[t] += sd[t + off];
        __syncthreads();
    }
    if (t == 0) part[b] = sd[0];
}

__global__ __launch_bounds__(256) void k_scan_top(int* __restrict__ part, int nb)
{
    __shared__ int sd[256];
    const int t = threadIdx.x;
    const int orig = (t < nb) ? part[t] : 0;
    sd[t] = orig;
    __syncthreads();
    for (int off = 1; off < 256; off <<= 1) {
        const int v = (t >= off) ? sd[t - off] : 0;
        __syncthreads();
        sd[t] += v;
        __syncthreads();
    }
    if (t < nb) part[t] = sd[t] - orig;   // exclusive
}

__global__ __launch_bounds__(256) void k_scan_final(const int* __restrict__ deg,
                                                    const int* __restrict__ part,
                                                    int* __restrict__ row_start,
                                                    int* __restrict__ cursor, int N)
{
    __shared__ int ts[256];
    const int b = blockIdx.x, t = threadIdx.x;
    const int base = b * SCAN_CHUNK + t * 4;
    int v[4]; int s = 0;
#pragma unroll
    for (int i = 0; i < 4; ++i) { const int idx = base + i; v[i] = (idx < N) ? deg[idx] : 0; s += v[i]; }
    ts[t] = s; __syncthreads();
    for (int off = 1; off < 256; off <<= 1) {
        const int vv = (t >= off) ? ts[t - off] : 0;
        __syncthreads();
        ts[t] += vv;
        __syncthreads();
    }
    int run = part[b] + ((t > 0) ? ts[t - 1] : 0);
#pragma unroll
    for (int i = 0; i < 4; ++i) {
        const int idx = base + i;
        if (idx < N) { row_start[idx] = run; cursor[idx] = run; run += v[i]; }
    }
}

// scatter: record CSR position per edge AND src node per CSR slot
__global__ __launch_bounds__(256) void k_scatter(const int* __restrict__ ei,
                                                 int* __restrict__ cursor,
                                                 int* __restrict__ epos,
                                                 int* __restrict__ esrc, int E)
{
    const int e = blockIdx.x * 256 + threadIdx.x;
    if (e < E) {
        const int pos = atomicAdd(&cursor[ei[E + e]], 1);
        epos[e] = pos;
        esrc[pos] = ei[e];
    }
}

// ---------------------------------------------------------------- aggregation: 1 wave / dst node, 2 edges in flight
__global__ __launch_bounds__(256) void k_aggr(
    const int* __restrict__ esrc, const int* __restrict__ row_start,
    const int* __restrict__ deg, const float* __restrict__ V,
    const float* __restrict__ exp_, float* __restrict__ aggr, int N)
{
    const int tid = threadIdx.x;
    const int n = blockIdx.x * 4 + (tid >> 6);
    if (n >= N) return;
    const int lane = tid & 63;
    const int sub = lane >> 5;        // which edge of the pair
    const int l = lane & 31;
    const int h = l >> 2;
    const int c0 = l * 4;
    const int rs = row_start[n];
    const int dg = deg[n];
    float4 acc = make_float4(0.f, 0.f, 0.f, 0.f);
    for (int j = sub; j < dg; j += 2) {
        const int idx = rs + j;
        const int s = esrc[idx];                           // 1-deep chain
        const float a = exp_[(size_t)idx * 8 + h];         // index-derived addr
        const float4 v = *(const float4*)(V + (size_t)s * 128 + c0);  // V pre-scaled by 1/ssum
        acc.x = fmaf(v.x, a, acc.x);
        acc.y = fmaf(v.y, a, acc.y);
        acc.z = fmaf(v.z, a, acc.z);
        acc.w = fmaf(v.w, a, acc.w);
    }
    acc.x += __shfl_xor(acc.x, 32, 64);
    acc.y += __shfl_xor(acc.y, 32, 64);
    acc.z += __shfl_xor(acc.z, 32, 64);
    acc.w += __shfl_xor(acc.w, 32, 64);
    if (sub == 0) *(float4*)(aggr + (size_t)n * 128 + c0) = acc;
}

// ---------------------------------------------------------------- launch
extern "C" void kernel_launch(void* const* d_in, const int* in_sizes, int n_in,
                              void* d_out, int out_size, void* d_ws, size_t ws_size,
                              hipStream_t stream)
{
    const float* x    = (const float*)d_in[0];
    const int*   ei   = (const int*)d_in[1];
    const float* nt   = (const float*)d_in[2];
    const float* et   = (const float*)d_in[3];
    const float* mW1  = (const float*)d_in[4];
    const float* mb1  = (const float*)d_in[5];
    const float* m_g  = (const float*)d_in[6];
    const float* m_b  = (const float*)d_in[7];
    const float* m_m  = (const float*)d_in[8];
    const float* m_v  = (const float*)d_in[9];
    const float* mW2  = (const float*)d_in[10];
    const float* mb2  = (const float*)d_in[11];
    const float* resW = (const float*)d_in[12];
    const float* qW   = (const float*)d_in[13];
    const float* qb   = (const float*)d_in[14];
    const float* kW   = (const float*)d_in[15];
    const float* kb   = (const float*)d_in[16];
    const float* vW   = (const float*)d_in[17];
    const float* vb   = (const float*)d_in[18];
    const float* oW1  = (const float*)d_in[19];
    const float* ob1  = (const float*)d_in[20];
    const float* o_g  = (const float*)d_in[21];
    const float* o_b  = (const float*)d_in[22];
    const float* o_m  = (const float*)d_in[23];
    const float* o_v  = (const float*)d_in[24];
    const float* oW2  = (const float*)d_in[25];
    const float* ob2  = (const float*)d_in[26];
    float* out = (float*)d_out;

    const int N = in_sizes[0] / 128;
    const int E = in_sizes[1] / 2;

    // workspace layout (floats): eaq|eak | Q | K | V | exp | ssum | [ints] deg,row_start,cursor,part,epos,esrc
    float* ws   = (float*)d_ws;
    float* eaq  = ws;
    float* eak  = ws + 128;
    float* Q    = ws + 256;
    float* K    = Q + (size_t)N * 128;
    float* V    = K + (size_t)N * 128;
    float* exp_ = V + (size_t)N * 128;
    float* ssum = exp_ + (size_t)E * 8;
    int* deg       = (int*)(ssum + (size_t)N * 8);
    int* row_start = deg + N;
    int* cursor    = row_start + N;
    int* part      = cursor + N;
    int* epos      = part + 256;
    int* esrc      = epos + E;
    float* aggr = Q;          // Q dead after edge pass 1
    // bf16 weight planes live in dead regions:
    //   qkv planes in ssum (consumed by k_mm_qkv BEFORE ssum memset)
    //   out planes in exp_ (written AFTER k_aggr, when exp_ is dead)
    ushort* Pq = (ushort*)ssum;   // 3 * 32768 ushorts = 192 KB  (<< N*8 floats)
    ushort* Po = (ushort*)exp_;   // 192 KB  (<< E*8 floats)

    const int nbm  = (N + BM - 1) / BM;
    const int nbsc = (N + SCAN_CHUNK - 1) / SCAN_CHUNK;   // scan blocks (<=256)

    // --- weight prep + ea (before memsets; Pq aliases ssum) ---
    k_prep3<<<dim3(128, 3), 128, 0, stream>>>(qW, kW, vW, Pq);
    k_ea<<<1, 128, 0, stream>>>(nt, et, mW1, mb1, m_g, m_b, m_m, m_v, mW2, mb2,
                                qW, qb, kW, kb, eaq, eak);
    k_mm_qkv<<<dim3(nbm, 3), 512, 0, stream>>>(x, Pq, eaq, eak, vb, Q, K, V, N);

    // planes consumed -> now zero ssum/deg (stream-ordered)
    hipMemsetAsync(ssum, 0, (size_t)N * 8 * sizeof(float), stream);
    hipMemsetAsync(deg, 0, (size_t)N * sizeof(int), stream);

    // CSR build (independent of Q/K/V values)
    k_hist<<<(E + 255) / 256, 256, 0, stream>>>(ei, deg, E);
    k_scan_partial<<<nbsc, 256, 0, stream>>>(deg, part, N);
    k_scan_top<<<1, 256, 0, stream>>>(part, nbsc);
    k_scan_final<<<nbsc, 256, 0, stream>>>(deg, part, row_start, cursor, N);
    k_scatter<<<(E + 255) / 256, 256, 0, stream>>>(ei, cursor, epos, esrc, E);

    k_edge1<<<(int)(((size_t)E * 8 + 255) / 256), 256, 0, stream>>>(ei, Q, K, epos, exp_, ssum, E);
    k_vscale<<<(N * 32 + 255) / 256, 256, 0, stream>>>(V, ssum, N);
    k_aggr<<<(N + 3) / 4, 256, 0, stream>>>(esrc, row_start, deg, V, exp_, aggr, N);

    // --- fused output chain via MFMA (exp_ dead now; Po aliases it) ---
    k_prep3<<<dim3(128, 3), 128, 0, stream>>>(resW, oW1, oW2, Po);
    k_out_fused<<<nbm, 512, 0, stream>>>(x, Po, aggr, ob1, o_m, o_v, o_g, o_b, ob2, out, N);
}

// Round 3
// 529.289 us; speedup vs baseline: 1.3964x; 1.0480x over previous
//
#include <hip/hip_runtime.h>

#define BN_EPS 1e-5f
#define SCAN_CHUNK 1024  // elements per scan block (256 thr x 4)
#define BM 128           // rows per MFMA-GEMM block
#define ZSTRIDE 132      // f32 t-tile LDS row stride (528 B, 16B-aligned)

typedef __attribute__((ext_vector_type(8))) short s16x8;
typedef __attribute__((ext_vector_type(4))) float f32x4;

// ---------------------------------------------------------------- ea MLP + folded Q/K biases
__global__ __launch_bounds__(128) void k_ea(
    const float* __restrict__ nt, const float* __restrict__ et,
    const float* __restrict__ mW1, const float* __restrict__ mb1,
    const float* __restrict__ m_g, const float* __restrict__ m_b,
    const float* __restrict__ m_m, const float* __restrict__ m_v,
    const float* __restrict__ mW2, const float* __restrict__ mb2,
    const float* __restrict__ qW, const float* __restrict__ qb,
    const float* __restrict__ kW, const float* __restrict__ kb,
    float* __restrict__ eaq, float* __restrict__ eak)
{
    __shared__ float merged[256];
    __shared__ float h[128];
    __shared__ float sea[128];
    const int t = threadIdx.x;
    merged[t]       = nt[t];
    merged[128 + t] = et[t];
    __syncthreads();
    float acc = mb1[t];
    for (int i = 0; i < 256; ++i) acc = fmaf(merged[i], mW1[i * 128 + t], acc);
    acc = (acc - m_m[t]) * rsqrtf(m_v[t] + BN_EPS) * m_g[t] + m_b[t];
    h[t] = acc > 0.f ? acc : 0.f;
    __syncthreads();
    float acc2 = mb2[t];
    for (int k = 0; k < 128; ++k) acc2 = fmaf(h[k], mW2[k * 128 + t], acc2);
    sea[t] = acc2;
    __syncthreads();
    float aq = qb[t], ak = kb[t];
    for (int k = 0; k < 128; ++k) {
        const float e = sea[k];
        aq = fmaf(e, qW[k * 128 + t], aq);
        ak = fmaf(e, kW[k * 128 + t], ak);
    }
    eaq[t] = aq;
    eak[t] = ak;
}

// ---------------------------------------------------------------- bf16 hi/lo split helper
__device__ __forceinline__ void split_store(float w, ushort* __restrict__ base,
                                            int j, int k)
{
    unsigned u = __builtin_bit_cast(unsigned, w);
    unsigned hi = (u + 0x7fffu + ((u >> 16) & 1u)) >> 16;   // RNE to bf16
    float hif = __builtin_bit_cast(float, hi << 16);
    float res = w - hif;
    unsigned lo = __builtin_bit_cast(unsigned, res) >> 16;  // trunc of residual
    base[j * 128 + k]         = (ushort)hi;
    base[16384 + j * 128 + k] = (ushort)lo;
}

// ---------------------------------------------------------------- weight prep: W[k][j] -> transposed bf16 hi/lo planes
__global__ __launch_bounds__(128) void k_prep3(
    const float* __restrict__ W0, const float* __restrict__ W1,
    const float* __restrict__ W2, ushort* __restrict__ P)
{
    const int j = blockIdx.x;   // output column of W = row of Wt
    const int m = blockIdx.y;
    const int k = threadIdx.x;
    const float* W = (m == 0) ? W0 : (m == 1) ? W1 : W2;
    split_store(W[k * 128 + j], P + (size_t)m * 32768, j, k);
}

// out-chain prep: plane0 = Wa = resW@oW1 (fused residual path), plane1 = oW1, plane2 = oW2
__global__ __launch_bounds__(128) void k_prep_out(
    const float* __restrict__ resW, const float* __restrict__ oW1,
    const float* __restrict__ oW2, ushort* __restrict__ P)
{
    __shared__ float col[128];
    const int j = blockIdx.x;
    const int m = blockIdx.y;
    const int k = threadIdx.x;
    float w;
    if (m == 0) {
        col[k] = oW1[k * 128 + j];          // column j of oW1
        __syncthreads();
        float acc = 0.f;
        for (int i = 0; i < 128; ++i) acc = fmaf(resW[k * 128 + i], col[i], acc);
        w = acc;                             // Wa[k][j]
    } else {
        const float* W = (m == 1) ? oW1 : oW2;
        w = W[k * 128 + j];
    }
    split_store(w, P + (size_t)m * 32768, j, k);
}

// ---------------------------------------------------------------- MFMA GEMM core (bf16x3)
// LDS sw: two planes of Wt in bf16, each [128][128] with XOR swizzle
// byte ^= (row&7)<<4  (breaks the 16-way conflict of the 256B row stride).
template <int NT>
__device__ __forceinline__ void stage_w(const ushort* __restrict__ wpl,
                                        ushort* __restrict__ sw, int tid)
{
    const uint4* src = (const uint4*)wpl;   // 4096 uint4 = hi plane then lo plane
#pragma unroll
    for (int it = 0; it < 4096 / NT; ++it) {
        const int idx = it * NT + tid;
        const uint4 v = src[idx];
        const int plane = idx >> 11;
        const int rr = (idx >> 4) & 127;
        const int cb = (idx & 15) << 4;                       // byte offset in row
        const int byteoff = ((rr * 256 + cb) ^ ((rr & 7) << 4));
        *(uint4*)((char*)sw + plane * 32768 + byteoff) = v;
    }
}

// A-fragment k-slots and B-fragment k-slots use the SAME (group, j) -> k
// convention, so the result is invariant to the HW's internal k permutation.
// Arow may point to global memory or to an LDS f32 tile.
template <int CT>
__device__ __forceinline__ void mm_core(const float* __restrict__ Arow,
                                        const ushort* __restrict__ sw,
                                        int g, int r16, int ct0, f32x4* acc)
{
#pragma unroll
    for (int ks = 0; ks < 4; ++ks) {
        const float* ap = Arow + ks * 32 + g * 8;
        const float4 a0 = *(const float4*)(ap);
        const float4 a1 = *(const float4*)(ap + 4);
        float av[8] = {a0.x, a0.y, a0.z, a0.w, a1.x, a1.y, a1.z, a1.w};
        s16x8 ahi, alo;
#pragma unroll
        for (int j = 0; j < 8; ++j) {
            const unsigned u = __builtin_bit_cast(unsigned, av[j]);
            ahi[j] = (short)(u >> 16);
            const float hif = __builtin_bit_cast(float, u & 0xffff0000u);
            const float res = av[j] - hif;
            alo[j] = (short)(__builtin_bit_cast(unsigned, res) >> 16);
        }
        const int koff = ks * 64 + g * 16;   // bytes within a Wt row
#pragma unroll
        for (int ct = 0; ct < CT; ++ct) {
            const int row = (ct0 + ct) * 16 + r16;
            const int byteoff = ((row * 256 + koff) ^ ((row & 7) << 4));
            const s16x8 bhi = *(const s16x8*)((const char*)sw + byteoff);
            const s16x8 blo = *(const s16x8*)((const char*)sw + 32768 + byteoff);
            acc[ct] = __builtin_amdgcn_mfma_f32_16x16x32_bf16(ahi, bhi, acc[ct], 0, 0, 0);
            acc[ct] = __builtin_amdgcn_mfma_f32_16x16x32_bf16(ahi, blo, acc[ct], 0, 0, 0);
            acc[ct] = __builtin_amdgcn_mfma_f32_16x16x32_bf16(alo, bhi, acc[ct], 0, 0, 0);
        }
    }
}

// ---------------------------------------------------------------- Q/K/V via MFMA (blockIdx.y selects matrix)
__global__ __launch_bounds__(512, 4) void k_mm_qkv(
    const float* __restrict__ x, const ushort* __restrict__ planes,
    const float* __restrict__ eaq, const float* __restrict__ eak,
    const float* __restrict__ vb,
    float* __restrict__ Q, float* __restrict__ K, float* __restrict__ V, int N)
{
    __shared__ ushort sw[2 * 128 * 128];   // 64 KB
    const int tid = threadIdx.x;
    const int sel = blockIdx.y;
    stage_w<512>(planes + (size_t)sel * 32768, sw, tid);
    __syncthreads();

    const int wave = tid >> 6, lane = tid & 63;
    const int g = lane >> 4, r16 = lane & 15;
    const int n0 = blockIdx.x * BM + wave * 16;
    int nA = n0 + r16; if (nA >= N) nA = N - 1;

    f32x4 acc[8];
#pragma unroll
    for (int ct = 0; ct < 8; ++ct) acc[ct] = (f32x4){0.f, 0.f, 0.f, 0.f};
    mm_core<8>(x + (size_t)nA * 128, sw, g, r16, 0, acc);

    const float* bias = (sel == 0) ? eaq : (sel == 1) ? eak : vb;
    float* O          = (sel == 0) ? Q   : (sel == 1) ? K   : V;
    const float scale = (sel == 0) ? 0.25f : 1.0f;
#pragma unroll
    for (int ct = 0; ct < 8; ++ct) {
        const int c = ct * 16 + r16;
        const float bc = bias[c];
#pragma unroll
        for (int r = 0; r < 4; ++r) {
            const int n = n0 + g * 4 + r;   // D row = (lane>>4)*4 + reg  [m89]
            if (n < N) O[(size_t)n * 128 + c] = (acc[ct][r] + bc) * scale;
        }
    }
}

// ---------------------------------------------------------------- fused out chain, 16 waves:
// u = x@Wa + aggr@oW1 + ob1 (Wa = resW@oW1 precomputed; z eliminated algebraically)
// t = lrelu(bn(u)) [LDS]; out = t@oW2 + ob2.
// wave w: row-group w&7 (16 rows), col-half w>>3 (4 of 8 ct tiles).
__global__ __launch_bounds__(1024, 4) void k_out2(
    const float* __restrict__ x, const ushort* __restrict__ Po,
    const float* __restrict__ aggr,
    const float* __restrict__ ob1,
    const float* __restrict__ o_m, const float* __restrict__ o_v,
    const float* __restrict__ o_g, const float* __restrict__ o_b,
    const float* __restrict__ ob2,
    float* __restrict__ out, int N)
{
    __shared__ ushort sw[2 * 128 * 128];     // 64 KB   (current weight, bf16 hi/lo)
    __shared__ float  tb[128 * ZSTRIDE];     // 67.6 KB (t tile, f32)
    const int tid = threadIdx.x;
    const int wave = tid >> 6, lane = tid & 63;
    const int g = lane >> 4, r16 = lane & 15;
    const int wr = wave & 7, wc = wave >> 3;
    const int ct0 = wc * 4;
    const int n0 = blockIdx.x * BM;
    const int arow = wr * 16 + r16;                 // block-relative A row
    int nA = n0 + arow; if (nA >= N) nA = N - 1;

    f32x4 acc[4];
#pragma unroll
    for (int ct = 0; ct < 4; ++ct) acc[ct] = (f32x4){0.f, 0.f, 0.f, 0.f};

    // ---- GEMM1a: x @ Wa ----
    stage_w<1024>(Po, sw, tid);
    __syncthreads();
    mm_core<4>(x + (size_t)nA * 128, sw, g, r16, ct0, acc);
    __syncthreads();                                // sw reads done

    // ---- GEMM1b: += aggr @ oW1 ----
    stage_w<1024>(Po + 32768, sw, tid);
    __syncthreads();
    mm_core<4>(aggr + (size_t)nA * 128, sw, g, r16, ct0, acc);
    __syncthreads();                                // sw reads done

    // ---- epilogue: t = lrelu(bn(u + ob1)) -> tb ----
#pragma unroll
    for (int ct = 0; ct < 4; ++ct) {
        const int c = (ct0 + ct) * 16 + r16;
        const float bc = ob1[c];
        const float rs = rsqrtf(o_v[c] + BN_EPS);
        const float mm = o_m[c], gg = o_g[c], bb = o_b[c];
#pragma unroll
        for (int r = 0; r < 4; ++r) {
            const int nrel = wr * 16 + g * 4 + r;
            float u = acc[ct][r] + bc;
            u = (u - mm) * rs * gg + bb;
            u = u > 0.f ? u : 0.01f * u;
            tb[nrel * ZSTRIDE + c] = u;
        }
    }
    stage_w<1024>(Po + 65536, sw, tid);             // overlap oW2 staging with t writes
    __syncthreads();                                // tb complete + sw staged

    // ---- GEMM3: out = t @ oW2 + ob2 ----
#pragma unroll
    for (int ct = 0; ct < 4; ++ct) acc[ct] = (f32x4){0.f, 0.f, 0.f, 0.f};
    mm_core<4>(tb + arow * ZSTRIDE, sw, g, r16, ct0, acc);
#pragma unroll
    for (int ct = 0; ct < 4; ++ct) {
        const int c = (ct0 + ct) * 16 + r16;
        const float bc = ob2[c];
#pragma unroll
        for (int r = 0; r < 4; ++r) {
            const int n = n0 + wr * 16 + g * 4 + r;
            if (n < N) out[(size_t)n * 128 + c] = acc[ct][r] + bc;
        }
    }
}

// ---------------------------------------------------------------- edge pass 1: ex (CSR-permuted) + ssum
__global__ __launch_bounds__(256) void k_edge1(
    const int* __restrict__ ei, const float* __restrict__ Q,
    const float* __restrict__ K, const int* __restrict__ epos,
    float* __restrict__ exp_, float* __restrict__ ssum, int E)
{
    const int t = blockIdx.x * 256 + threadIdx.x;   // one (edge, head) per thread
    const int e = t >> 3;
    if (e >= E) return;
    const int h = t & 7;
    const int s = ei[e];
    const int d = ei[E + e];
    const float* qp = Q + (size_t)s * 128 + h * 16;
    const float* kp = K + (size_t)d * 128 + h * 16;
    float acc = 0.f;
#pragma unroll
    for (int r = 0; r < 4; ++r) {
        const float4 a = *(const float4*)(qp + r * 4);
        const float4 b = *(const float4*)(kp + r * 4);
        acc += a.x * b.x + a.y * b.y + a.z * b.z + a.w * b.w;
    }
    const float v = __expf(acc);   // |score| small; no max-subtraction needed
    exp_[(size_t)epos[e] * 8 + h] = v;              // CSR order
    unsafeAtomicAdd(&ssum[(size_t)s * 8 + h], v);
}

// ---------------------------------------------------------------- V[s,h,:] *= 1/ssum[s,h]  (in place)
__global__ __launch_bounds__(256) void k_vscale(
    float* __restrict__ V, const float* __restrict__ ssum, int N)
{
    const int i = blockIdx.x * 256 + threadIdx.x;   // float4 index
    if (i >= N * 32) return;
    const int row = i >> 5, q = i & 31, h = q >> 2;
    const float r = 1.0f / ssum[(size_t)row * 8 + h];
    float4 v = *(float4*)(V + (size_t)i * 4);
    v.x *= r; v.y *= r; v.z *= r; v.w *= r;
    *(float4*)(V + (size_t)i * 4) = v;
}

// ---------------------------------------------------------------- CSR build (dst)
__global__ __launch_bounds__(256) void k_hist(const int* __restrict__ ei,
                                              int* __restrict__ deg, int E)
{
    const int e = blockIdx.x * 256 + threadIdx.x;
    if (e < E) atomicAdd(&deg[ei[E + e]], 1);
}

__global__ __launch_bounds__(256) void k_scan_partial(const int* __restrict__ deg,
                                                      int* __restrict__ part, int N)
{
    __shared__ int sd[256];
    const int b = blockIdx.x, t = threadIdx.x;
    const int base = b * SCAN_CHUNK + t * 4;
    int s = 0;
#pragma unroll
    for (int i = 0; i < 4; ++i) { const int idx = base + i; if (idx < N) s += deg[idx]; }
    sd[t] = s; __syncthreads();
    for (int off = 128; off > 0; off >>= 1) {
        if (t < off) sd[t] += sd[t + off];
        __syncthreads();
    }
    if (t == 0) part[b] = sd[0];
}

__global__ __launch_bounds__(256) void k_scan_top(int* __restrict__ part, int nb)
{
    __shared__ int sd[256];
    const int t = threadIdx.x;
    const int orig = (t < nb) ? part[t] : 0;
    sd[t] = orig;
    __syncthreads();
    for (int off = 1; off < 256; off <<= 1) {
        const int v = (t >= off) ? sd[t - off] : 0;
        __syncthreads();
        sd[t] += v;
        __syncthreads();
    }
    if (t < nb) part[t] = sd[t] - orig;   // exclusive
}

__global__ __launch_bounds__(256) void k_scan_final(const int* __restrict__ deg,
                                                    const int* __restrict__ part,
                                                    int* __restrict__ row_start,
                                                    int* __restrict__ cursor, int N)
{
    __shared__ int ts[256];
    const int b = blockIdx.x, t = threadIdx.x;
    const int base = b * SCAN_CHUNK + t * 4;
    int v[4]; int s = 0;
#pragma unroll
    for (int i = 0; i < 4; ++i) { const int idx = base + i; v[i] = (idx < N) ? deg[idx] : 0; s += v[i]; }
    ts[t] = s; __syncthreads();
    for (int off = 1; off < 256; off <<= 1) {
        const int vv = (t >= off) ? ts[t - off] : 0;
        __syncthreads();
        ts[t] += vv;
        __syncthreads();
    }
    int run = part[b] + ((t > 0) ? ts[t - 1] : 0);
#pragma unroll
    for (int i = 0; i < 4; ++i) {
        const int idx = base + i;
        if (idx < N) { row_start[idx] = run; cursor[idx] = run; run += v[i]; }
    }
}

// scatter: record CSR position per edge AND src node per CSR slot
__global__ __launch_bounds__(256) void k_scatter(const int* __restrict__ ei,
                                                 int* __restrict__ cursor,
                                                 int* __restrict__ epos,
                                                 int* __restrict__ esrc, int E)
{
    const int e = blockIdx.x * 256 + threadIdx.x;
    if (e < E) {
        const int pos = atomicAdd(&cursor[ei[E + e]], 1);
        epos[e] = pos;
        esrc[pos] = ei[e];
    }
}

// ---------------------------------------------------------------- aggregation: 1 wave / dst node, 2 edges in flight
__global__ __launch_bounds__(256) void k_aggr(
    const int* __restrict__ esrc, const int* __restrict__ row_start,
    const int* __restrict__ deg, const float* __restrict__ V,
    const float* __restrict__ exp_, float* __restrict__ aggr, int N)
{
    const int tid = threadIdx.x;
    const int n = blockIdx.x * 4 + (tid >> 6);
    if (n >= N) return;
    const int lane = tid & 63;
    const int sub = lane >> 5;        // which edge of the pair
    const int l = lane & 31;
    const int h = l >> 2;
    const int c0 = l * 4;
    const int rs = row_start[n];
    const int dg = deg[n];
    float4 acc = make_float4(0.f, 0.f, 0.f, 0.f);
    for (int j = sub; j < dg; j += 2) {
        const int idx = rs + j;
        const int s = esrc[idx];                           // 1-deep chain
        const float a = exp_[(size_t)idx * 8 + h];         // index-derived addr
        const float4 v = *(const float4*)(V + (size_t)s * 128 + c0);  // V pre-scaled by 1/ssum
        acc.x = fmaf(v.x, a, acc.x);
        acc.y = fmaf(v.y, a, acc.y);
        acc.z = fmaf(v.z, a, acc.z);
        acc.w = fmaf(v.w, a, acc.w);
    }
    acc.x += __shfl_xor(acc.x, 32, 64);
    acc.y += __shfl_xor(acc.y, 32, 64);
    acc.z += __shfl_xor(acc.z, 32, 64);
    acc.w += __shfl_xor(acc.w, 32, 64);
    if (sub == 0) *(float4*)(aggr + (size_t)n * 128 + c0) = acc;
}

// ---------------------------------------------------------------- launch
extern "C" void kernel_launch(void* const* d_in, const int* in_sizes, int n_in,
                              void* d_out, int out_size, void* d_ws, size_t ws_size,
                              hipStream_t stream)
{
    const float* x    = (const float*)d_in[0];
    const int*   ei   = (const int*)d_in[1];
    const float* nt   = (const float*)d_in[2];
    const float* et   = (const float*)d_in[3];
    const float* mW1  = (const float*)d_in[4];
    const float* mb1  = (const float*)d_in[5];
    const float* m_g  = (const float*)d_in[6];
    const float* m_b  = (const float*)d_in[7];
    const float* m_m  = (const float*)d_in[8];
    const float* m_v  = (const float*)d_in[9];
    const float* mW2  = (const float*)d_in[10];
    const float* mb2  = (const float*)d_in[11];
    const float* resW = (const float*)d_in[12];
    const float* qW   = (const float*)d_in[13];
    const float* qb   = (const float*)d_in[14];
    const float* kW   = (const float*)d_in[15];
    const float* kb   = (const float*)d_in[16];
    const float* vW   = (const float*)d_in[17];
    const float* vb   = (const float*)d_in[18];
    const float* oW1  = (const float*)d_in[19];
    const float* ob1  = (const float*)d_in[20];
    const float* o_g  = (const float*)d_in[21];
    const float* o_b  = (const float*)d_in[22];
    const float* o_m  = (const float*)d_in[23];
    const float* o_v  = (const float*)d_in[24];
    const float* oW2  = (const float*)d_in[25];
    const float* ob2  = (const float*)d_in[26];
    float* out = (float*)d_out;

    const int N = in_sizes[0] / 128;
    const int E = in_sizes[1] / 2;

    // workspace layout (floats): eaq|eak | Q | K | V | exp | ssum | [ints] deg,row_start,cursor,part,epos,esrc
    float* ws   = (float*)d_ws;
    float* eaq  = ws;
    float* eak  = ws + 128;
    float* Q    = ws + 256;
    float* K    = Q + (size_t)N * 128;
    float* V    = K + (size_t)N * 128;
    float* exp_ = V + (size_t)N * 128;
    float* ssum = exp_ + (size_t)E * 8;
    int* deg       = (int*)(ssum + (size_t)N * 8);
    int* row_start = deg + N;
    int* cursor    = row_start + N;
    int* part      = cursor + N;
    int* epos      = part + 256;
    int* esrc      = epos + E;
    float* aggr = Q;          // Q dead after edge pass 1
    // bf16 weight planes live in dead regions:
    //   qkv planes in ssum (consumed by k_mm_qkv BEFORE ssum memset)
    //   out planes in exp_ (written AFTER k_aggr, when exp_ is dead)
    ushort* Pq = (ushort*)ssum;   // 3 * 32768 ushorts = 192 KB  (<< N*8 floats)
    ushort* Po = (ushort*)exp_;   // 192 KB  (<< E*8 floats)

    const int nbm  = (N + BM - 1) / BM;
    const int nbsc = (N + SCAN_CHUNK - 1) / SCAN_CHUNK;   // scan blocks (<=256)

    // --- weight prep + ea (before memsets; Pq aliases ssum) ---
    k_prep3<<<dim3(128, 3), 128, 0, stream>>>(qW, kW, vW, Pq);
    k_ea<<<1, 128, 0, stream>>>(nt, et, mW1, mb1, m_g, m_b, m_m, m_v, mW2, mb2,
                                qW, qb, kW, kb, eaq, eak);
    k_mm_qkv<<<dim3(nbm, 3), 512, 0, stream>>>(x, Pq, eaq, eak, vb, Q, K, V, N);

    // planes consumed -> now zero ssum/deg (stream-ordered)
    hipMemsetAsync(ssum, 0, (size_t)N * 8 * sizeof(float), stream);
    hipMemsetAsync(deg, 0, (size_t)N * sizeof(int), stream);

    // CSR build (independent of Q/K/V values)
    k_hist<<<(E + 255) / 256, 256, 0, stream>>>(ei, deg, E);
    k_scan_partial<<<nbsc, 256, 0, stream>>>(deg, part, N);
    k_scan_top<<<1, 256, 0, stream>>>(part, nbsc);
    k_scan_final<<<nbsc, 256, 0, stream>>>(deg, part, row_start, cursor, N);
    k_scatter<<<(E + 255) / 256, 256, 0, stream>>>(ei, cursor, epos, esrc, E);

    k_edge1<<<(int)(((size_t)E * 8 + 255) / 256), 256, 0, stream>>>(ei, Q, K, epos, exp_, ssum, E);
    k_vscale<<<(N * 32 + 255) / 256, 256, 0, stream>>>(V, ssum, N);
    k_aggr<<<(N + 3) / 4, 256, 0, stream>>>(esrc, row_start, deg, V, exp_, aggr, N);

    // --- fused output chain via MFMA (exp_ dead now; Po aliases it) ---
    k_prep_out<<<dim3(128, 3), 128, 0, stream>>>(resW, oW1, oW2, Po);
    k_out2<<<nbm, 1024, 0, stream>>>(x, Po, aggr, ob1, o_m, o_v, o_g, o_b, ob2, out, N);
}

// Round 4
// 496.865 us; speedup vs baseline: 1.4875x; 1.0653x over previous
//
#include <hip/hip_runtime.h>

#define BN_EPS 1e-5f
#define SCAN_CHUNK 1024  // elements per scan block (256 thr x 4)
#define BM 128           // rows per MFMA-GEMM block
#define ZSTRIDE 132      // f32 t-tile LDS row stride (528 B, 16B-aligned)

typedef __attribute__((ext_vector_type(8))) short s16x8;
typedef __attribute__((ext_vector_type(4))) float f32x4;

// ---------------------------------------------------------------- ea MLP + folded Q/K biases
__global__ __launch_bounds__(128) void k_ea(
    const float* __restrict__ nt, const float* __restrict__ et,
    const float* __restrict__ mW1, const float* __restrict__ mb1,
    const float* __restrict__ m_g, const float* __restrict__ m_b,
    const float* __restrict__ m_m, const float* __restrict__ m_v,
    const float* __restrict__ mW2, const float* __restrict__ mb2,
    const float* __restrict__ qW, const float* __restrict__ qb,
    const float* __restrict__ kW, const float* __restrict__ kb,
    float* __restrict__ eaq, float* __restrict__ eak)
{
    __shared__ float merged[256];
    __shared__ float h[128];
    __shared__ float sea[128];
    const int t = threadIdx.x;
    merged[t]       = nt[t];
    merged[128 + t] = et[t];
    __syncthreads();
    float acc = mb1[t];
    for (int i = 0; i < 256; ++i) acc = fmaf(merged[i], mW1[i * 128 + t], acc);
    acc = (acc - m_m[t]) * rsqrtf(m_v[t] + BN_EPS) * m_g[t] + m_b[t];
    h[t] = acc > 0.f ? acc : 0.f;
    __syncthreads();
    float acc2 = mb2[t];
    for (int k = 0; k < 128; ++k) acc2 = fmaf(h[k], mW2[k * 128 + t], acc2);
    sea[t] = acc2;
    __syncthreads();
    float aq = qb[t], ak = kb[t];
    for (int k = 0; k < 128; ++k) {
        const float e = sea[k];
        aq = fmaf(e, qW[k * 128 + t], aq);
        ak = fmaf(e, kW[k * 128 + t], ak);
    }
    eaq[t] = aq;
    eak[t] = ak;
}

// ---------------------------------------------------------------- bf16 hi/lo split helper
__device__ __forceinline__ void split_store(float w, ushort* __restrict__ base,
                                            int j, int k)
{
    unsigned u = __builtin_bit_cast(unsigned, w);
    unsigned hi = (u + 0x7fffu + ((u >> 16) & 1u)) >> 16;   // RNE to bf16
    float hif = __builtin_bit_cast(float, hi << 16);
    float res = w - hif;
    unsigned lo = __builtin_bit_cast(unsigned, res) >> 16;  // trunc of residual
    base[j * 128 + k]         = (ushort)hi;
    base[16384 + j * 128 + k] = (ushort)lo;
}

// ---------------------------------------------------------------- weight prep: W[k][j] -> transposed bf16 hi/lo planes
__global__ __launch_bounds__(128) void k_prep3(
    const float* __restrict__ W0, const float* __restrict__ W1,
    const float* __restrict__ W2, ushort* __restrict__ P)
{
    const int j = blockIdx.x;   // output column of W = row of Wt
    const int m = blockIdx.y;
    const int k = threadIdx.x;
    const float* W = (m == 0) ? W0 : (m == 1) ? W1 : W2;
    split_store(W[k * 128 + j], P + (size_t)m * 32768, j, k);
}

// out-chain prep: plane0 = Wa = resW@oW1 (fused residual path), plane1 = oW1, plane2 = oW2
__global__ __launch_bounds__(128) void k_prep_out(
    const float* __restrict__ resW, const float* __restrict__ oW1,
    const float* __restrict__ oW2, ushort* __restrict__ P)
{
    __shared__ float col[128];
    const int j = blockIdx.x;
    const int m = blockIdx.y;
    const int k = threadIdx.x;
    float w;
    if (m == 0) {
        col[k] = oW1[k * 128 + j];          // column j of oW1
        __syncthreads();
        float acc = 0.f;
        for (int i = 0; i < 128; ++i) acc = fmaf(resW[k * 128 + i], col[i], acc);
        w = acc;                             // Wa[k][j]
    } else {
        const float* W = (m == 1) ? oW1 : oW2;
        w = W[k * 128 + j];
    }
    split_store(w, P + (size_t)m * 32768, j, k);
}

// ---------------------------------------------------------------- MFMA GEMM core (bf16x3)
// LDS sw: two planes of Wt in bf16, each [128][128] with XOR swizzle
// byte ^= (row&7)<<4  (breaks the 16-way conflict of the 256B row stride).
template <int NT>
__device__ __forceinline__ void stage_w(const ushort* __restrict__ wpl,
                                        ushort* __restrict__ sw, int tid)
{
    const uint4* src = (const uint4*)wpl;   // 4096 uint4 = hi plane then lo plane
#pragma unroll
    for (int it = 0; it < 4096 / NT; ++it) {
        const int idx = it * NT + tid;
        const uint4 v = src[idx];
        const int plane = idx >> 11;
        const int rr = (idx >> 4) & 127;
        const int cb = (idx & 15) << 4;                       // byte offset in row
        const int byteoff = ((rr * 256 + cb) ^ ((rr & 7) << 4));
        *(uint4*)((char*)sw + plane * 32768 + byteoff) = v;
    }
}

// A-fragment k-slots and B-fragment k-slots use the SAME (group, j) -> k
// convention, so the result is invariant to the HW's internal k permutation.
// Arow may point to global memory or to an LDS f32 tile.
template <int CT>
__device__ __forceinline__ void mm_core(const float* __restrict__ Arow,
                                        const ushort* __restrict__ sw,
                                        int g, int r16, int ct0, f32x4* acc)
{
#pragma unroll
    for (int ks = 0; ks < 4; ++ks) {
        const float* ap = Arow + ks * 32 + g * 8;
        const float4 a0 = *(const float4*)(ap);
        const float4 a1 = *(const float4*)(ap + 4);
        float av[8] = {a0.x, a0.y, a0.z, a0.w, a1.x, a1.y, a1.z, a1.w};
        s16x8 ahi, alo;
#pragma unroll
        for (int j = 0; j < 8; ++j) {
            const unsigned u = __builtin_bit_cast(unsigned, av[j]);
            ahi[j] = (short)(u >> 16);
            const float hif = __builtin_bit_cast(float, u & 0xffff0000u);
            const float res = av[j] - hif;
            alo[j] = (short)(__builtin_bit_cast(unsigned, res) >> 16);
        }
        const int koff = ks * 64 + g * 16;   // bytes within a Wt row
#pragma unroll
        for (int ct = 0; ct < CT; ++ct) {
            const int row = (ct0 + ct) * 16 + r16;
            const int byteoff = ((row * 256 + koff) ^ ((row & 7) << 4));
            const s16x8 bhi = *(const s16x8*)((const char*)sw + byteoff);
            const s16x8 blo = *(const s16x8*)((const char*)sw + 32768 + byteoff);
            acc[ct] = __builtin_amdgcn_mfma_f32_16x16x32_bf16(ahi, bhi, acc[ct], 0, 0, 0);
            acc[ct] = __builtin_amdgcn_mfma_f32_16x16x32_bf16(ahi, blo, acc[ct], 0, 0, 0);
            acc[ct] = __builtin_amdgcn_mfma_f32_16x16x32_bf16(alo, bhi, acc[ct], 0, 0, 0);
        }
    }
}

// ---------------------------------------------------------------- Q/K/V via MFMA (blockIdx.y selects matrix)
__global__ __launch_bounds__(512, 4) void k_mm_qkv(
    const float* __restrict__ x, const ushort* __restrict__ planes,
    const float* __restrict__ eaq, const float* __restrict__ eak,
    const float* __restrict__ vb,
    float* __restrict__ Q, float* __restrict__ K, float* __restrict__ V, int N)
{
    __shared__ ushort sw[2 * 128 * 128];   // 64 KB
    const int tid = threadIdx.x;
    const int sel = blockIdx.y;
    stage_w<512>(planes + (size_t)sel * 32768, sw, tid);
    __syncthreads();

    const int wave = tid >> 6, lane = tid & 63;
    const int g = lane >> 4, r16 = lane & 15;
    const int n0 = blockIdx.x * BM + wave * 16;
    int nA = n0 + r16; if (nA >= N) nA = N - 1;

    f32x4 acc[8];
#pragma unroll
    for (int ct = 0; ct < 8; ++ct) acc[ct] = (f32x4){0.f, 0.f, 0.f, 0.f};
    mm_core<8>(x + (size_t)nA * 128, sw, g, r16, 0, acc);

    const float* bias = (sel == 0) ? eaq : (sel == 1) ? eak : vb;
    float* O          = (sel == 0) ? Q   : (sel == 1) ? K   : V;
    const float scale = (sel == 0) ? 0.25f : 1.0f;
#pragma unroll
    for (int ct = 0; ct < 8; ++ct) {
        const int c = ct * 16 + r16;
        const float bc = bias[c];
#pragma unroll
        for (int r = 0; r < 4; ++r) {
            const int n = n0 + g * 4 + r;   // D row = (lane>>4)*4 + reg  [m89]
            if (n < N) O[(size_t)n * 128 + c] = (acc[ct][r] + bc) * scale;
        }
    }
}

// ---------------------------------------------------------------- fused out chain, 16 waves:
// u = x@Wa + aggr@oW1 + ob1 (Wa = resW@oW1 precomputed; z eliminated algebraically)
// t = lrelu(bn(u)) [LDS]; out = t@oW2 + ob2.
// wave w: row-group w&7 (16 rows), col-half w>>3 (4 of 8 ct tiles).
__global__ __launch_bounds__(1024, 4) void k_out2(
    const float* __restrict__ x, const ushort* __restrict__ Po,
    const float* __restrict__ aggr,
    const float* __restrict__ ob1,
    const float* __restrict__ o_m, const float* __restrict__ o_v,
    const float* __restrict__ o_g, const float* __restrict__ o_b,
    const float* __restrict__ ob2,
    float* __restrict__ out, int N)
{
    __shared__ ushort sw[2 * 128 * 128];     // 64 KB   (current weight, bf16 hi/lo)
    __shared__ float  tb[128 * ZSTRIDE];     // 67.6 KB (t tile, f32)
    const int tid = threadIdx.x;
    const int wave = tid >> 6, lane = tid & 63;
    const int g = lane >> 4, r16 = lane & 15;
    const int wr = wave & 7, wc = wave >> 3;
    const int ct0 = wc * 4;
    const int n0 = blockIdx.x * BM;
    const int arow = wr * 16 + r16;                 // block-relative A row
    int nA = n0 + arow; if (nA >= N) nA = N - 1;

    f32x4 acc[4];
#pragma unroll
    for (int ct = 0; ct < 4; ++ct) acc[ct] = (f32x4){0.f, 0.f, 0.f, 0.f};

    // ---- GEMM1a: x @ Wa ----
    stage_w<1024>(Po, sw, tid);
    __syncthreads();
    mm_core<4>(x + (size_t)nA * 128, sw, g, r16, ct0, acc);
    __syncthreads();                                // sw reads done

    // ---- GEMM1b: += aggr @ oW1 ----
    stage_w<1024>(Po + 32768, sw, tid);
    __syncthreads();
    mm_core<4>(aggr + (size_t)nA * 128, sw, g, r16, ct0, acc);
    __syncthreads();                                // sw reads done

    // ---- epilogue: t = lrelu(bn(u + ob1)) -> tb ----
#pragma unroll
    for (int ct = 0; ct < 4; ++ct) {
        const int c = (ct0 + ct) * 16 + r16;
        const float bc = ob1[c];
        const float rs = rsqrtf(o_v[c] + BN_EPS);
        const float mm = o_m[c], gg = o_g[c], bb = o_b[c];
#pragma unroll
        for (int r = 0; r < 4; ++r) {
            const int nrel = wr * 16 + g * 4 + r;
            float u = acc[ct][r] + bc;
            u = (u - mm) * rs * gg + bb;
            u = u > 0.f ? u : 0.01f * u;
            tb[nrel * ZSTRIDE + c] = u;
        }
    }
    stage_w<1024>(Po + 65536, sw, tid);             // overlap oW2 staging with t writes
    __syncthreads();                                // tb complete + sw staged

    // ---- GEMM3: out = t @ oW2 + ob2 ----
#pragma unroll
    for (int ct = 0; ct < 4; ++ct) acc[ct] = (f32x4){0.f, 0.f, 0.f, 0.f};
    mm_core<4>(tb + arow * ZSTRIDE, sw, g, r16, ct0, acc);
#pragma unroll
    for (int ct = 0; ct < 4; ++ct) {
        const int c = (ct0 + ct) * 16 + r16;
        const float bc = ob2[c];
#pragma unroll
        for (int r = 0; r < 4; ++r) {
            const int n = n0 + wr * 16 + g * 4 + r;
            if (n < N) out[(size_t)n * 128 + c] = acc[ct][r] + bc;
        }
    }
}

// ---------------------------------------------------------------- edge pass 1, CSR order: 1 wave / dst node,
// K[dst] resident in registers, 2 edges in flight (half-wave each).
// exp writes are SEQUENTIAL (CSR index = write position) -> epos eliminated.
__global__ __launch_bounds__(256) void k_edge1csr(
    const int* __restrict__ esrc, const int* __restrict__ row_start,
    const int* __restrict__ deg, const float* __restrict__ Q,
    const float* __restrict__ K, float* __restrict__ exp_,
    float* __restrict__ ssum, int N)
{
    const int tid = threadIdx.x;
    const int n = blockIdx.x * 4 + (tid >> 6);
    if (n >= N) return;
    const int lane = tid & 63;
    const int sub = lane >> 5;        // which edge of the pair
    const int l = lane & 31;
    const int h = l >> 2;             // head = element-range / 16
    const int c0 = l * 4;
    const int rs = row_start[n];
    const int dg = deg[n];
    // K[n] resident: float4 per lane (both half-waves hold the full row)
    const float4 kreg = *(const float4*)(K + (size_t)n * 128 + c0);
    for (int j = sub; j < dg; j += 2) {
        const int idx = rs + j;
        const int s = esrc[idx];                                  // 1-deep chain
        const float4 q = *(const float4*)(Q + (size_t)s * 128 + c0);
        float p = q.x * kreg.x + q.y * kreg.y + q.z * kreg.z + q.w * kreg.w;
        p += __shfl_xor(p, 1, 64);    // reduce across the 4-lane head group
        p += __shfl_xor(p, 2, 64);
        if ((l & 3) == 0) {
            const float v = __expf(p);    // |score| small; no max-subtraction needed
            exp_[(size_t)idx * 8 + h] = v;            // streaming write
            unsafeAtomicAdd(&ssum[(size_t)s * 8 + h], v);
        }
    }
}

// ---------------------------------------------------------------- V[s,h,:] *= 1/ssum[s,h]  (in place)
__global__ __launch_bounds__(256) void k_vscale(
    float* __restrict__ V, const float* __restrict__ ssum, int N)
{
    const int i = blockIdx.x * 256 + threadIdx.x;   // float4 index
    if (i >= N * 32) return;
    const int row = i >> 5, q = i & 31, h = q >> 2;
    const float r = 1.0f / ssum[(size_t)row * 8 + h];
    float4 v = *(float4*)(V + (size_t)i * 4);
    v.x *= r; v.y *= r; v.z *= r; v.w *= r;
    *(float4*)(V + (size_t)i * 4) = v;
}

// ---------------------------------------------------------------- CSR build (dst)
__global__ __launch_bounds__(256) void k_hist(const int* __restrict__ ei,
                                              int* __restrict__ deg, int E)
{
    const int e = blockIdx.x * 256 + threadIdx.x;
    if (e < E) atomicAdd(&deg[ei[E + e]], 1);
}

__global__ __launch_bounds__(256) void k_scan_partial(const int* __restrict__ deg,
                                                      int* __restrict__ part, int N)
{
    __shared__ int sd[256];
    const int b = blockIdx.x, t = threadIdx.x;
    const int base = b * SCAN_CHUNK + t * 4;
    int s = 0;
#pragma unroll
    for (int i = 0; i < 4; ++i) { const int idx = base + i; if (idx < N) s += deg[idx]; }
    sd[t] = s; __syncthreads();
    for (int off = 128; off > 0; off >>= 1) {
        if (t < off) sd[t] += sd[t + off];
        __syncthreads();
    }
    if (t == 0) part[b] = sd[0];
}

__global__ __launch_bounds__(256) void k_scan_top(int* __restrict__ part, int nb)
{
    __shared__ int sd[256];
    const int t = threadIdx.x;
    const int orig = (t < nb) ? part[t] : 0;
    sd[t] = orig;
    __syncthreads();
    for (int off = 1; off < 256; off <<= 1) {
        const int v = (t >= off) ? sd[t - off] : 0;
        __syncthreads();
        sd[t] += v;
        __syncthreads();
    }
    if (t < nb) part[t] = sd[t] - orig;   // exclusive
}

__global__ __launch_bounds__(256) void k_scan_final(const int* __restrict__ deg,
                                                    const int* __restrict__ part,
                                                    int* __restrict__ row_start,
                                                    int* __restrict__ cursor, int N)
{
    __shared__ int ts[256];
    const int b = blockIdx.x, t = threadIdx.x;
    const int base = b * SCAN_CHUNK + t * 4;
    int v[4]; int s = 0;
#pragma unroll
    for (int i = 0; i < 4; ++i) { const int idx = base + i; v[i] = (idx < N) ? deg[idx] : 0; s += v[i]; }
    ts[t] = s; __syncthreads();
    for (int off = 1; off < 256; off <<= 1) {
        const int vv = (t >= off) ? ts[t - off] : 0;
        __syncthreads();
        ts[t] += vv;
        __syncthreads();
    }
    int run = part[b] + ((t > 0) ? ts[t - 1] : 0);
#pragma unroll
    for (int i = 0; i < 4; ++i) {
        const int idx = base + i;
        if (idx < N) { row_start[idx] = run; cursor[idx] = run; run += v[i]; }
    }
}

// scatter: record src node per CSR slot
__global__ __launch_bounds__(256) void k_scatter(const int* __restrict__ ei,
                                                 int* __restrict__ cursor,
                                                 int* __restrict__ esrc, int E)
{
    const int e = blockIdx.x * 256 + threadIdx.x;
    if (e < E) {
        const int pos = atomicAdd(&cursor[ei[E + e]], 1);
        esrc[pos] = ei[e];
    }
}

// ---------------------------------------------------------------- aggregation: 1 wave / dst node, 2 edges in flight
__global__ __launch_bounds__(256) void k_aggr(
    const int* __restrict__ esrc, const int* __restrict__ row_start,
    const int* __restrict__ deg, const float* __restrict__ V,
    const float* __restrict__ exp_, float* __restrict__ aggr, int N)
{
    const int tid = threadIdx.x;
    const int n = blockIdx.x * 4 + (tid >> 6);
    if (n >= N) return;
    const int lane = tid & 63;
    const int sub = lane >> 5;        // which edge of the pair
    const int l = lane & 31;
    const int h = l >> 2;
    const int c0 = l * 4;
    const int rs = row_start[n];
    const int dg = deg[n];
    float4 acc = make_float4(0.f, 0.f, 0.f, 0.f);
    for (int j = sub; j < dg; j += 2) {
        const int idx = rs + j;
        const int s = esrc[idx];                           // 1-deep chain
        const float a = exp_[(size_t)idx * 8 + h];         // index-derived addr
        const float4 v = *(const float4*)(V + (size_t)s * 128 + c0);  // V pre-scaled by 1/ssum
        acc.x = fmaf(v.x, a, acc.x);
        acc.y = fmaf(v.y, a, acc.y);
        acc.z = fmaf(v.z, a, acc.z);
        acc.w = fmaf(v.w, a, acc.w);
    }
    acc.x += __shfl_xor(acc.x, 32, 64);
    acc.y += __shfl_xor(acc.y, 32, 64);
    acc.z += __shfl_xor(acc.z, 32, 64);
    acc.w += __shfl_xor(acc.w, 32, 64);
    if (sub == 0) *(float4*)(aggr + (size_t)n * 128 + c0) = acc;
}

// ---------------------------------------------------------------- launch
extern "C" void kernel_launch(void* const* d_in, const int* in_sizes, int n_in,
                              void* d_out, int out_size, void* d_ws, size_t ws_size,
                              hipStream_t stream)
{
    const float* x    = (const float*)d_in[0];
    const int*   ei   = (const int*)d_in[1];
    const float* nt   = (const float*)d_in[2];
    const float* et   = (const float*)d_in[3];
    const float* mW1  = (const float*)d_in[4];
    const float* mb1  = (const float*)d_in[5];
    const float* m_g  = (const float*)d_in[6];
    const float* m_b  = (const float*)d_in[7];
    const float* m_m  = (const float*)d_in[8];
    const float* m_v  = (const float*)d_in[9];
    const float* mW2  = (const float*)d_in[10];
    const float* mb2  = (const float*)d_in[11];
    const float* resW = (const float*)d_in[12];
    const float* qW   = (const float*)d_in[13];
    const float* qb   = (const float*)d_in[14];
    const float* kW   = (const float*)d_in[15];
    const float* kb   = (const float*)d_in[16];
    const float* vW   = (const float*)d_in[17];
    const float* vb   = (const float*)d_in[18];
    const float* oW1  = (const float*)d_in[19];
    const float* ob1  = (const float*)d_in[20];
    const float* o_g  = (const float*)d_in[21];
    const float* o_b  = (const float*)d_in[22];
    const float* o_m  = (const float*)d_in[23];
    const float* o_v  = (const float*)d_in[24];
    const float* oW2  = (const float*)d_in[25];
    const float* ob2  = (const float*)d_in[26];
    float* out = (float*)d_out;

    const int N = in_sizes[0] / 128;
    const int E = in_sizes[1] / 2;

    // workspace layout (floats): eaq|eak | Q | K | V | exp | ssum | [ints] deg,row_start,cursor,part,esrc
    float* ws   = (float*)d_ws;
    float* eaq  = ws;
    float* eak  = ws + 128;
    float* Q    = ws + 256;
    float* K    = Q + (size_t)N * 128;
    float* V    = K + (size_t)N * 128;
    float* exp_ = V + (size_t)N * 128;
    float* ssum = exp_ + (size_t)E * 8;
    int* deg       = (int*)(ssum + (size_t)N * 8);
    int* row_start = deg + N;
    int* cursor    = row_start + N;
    int* part      = cursor + N;
    int* esrc      = part + 256;
    float* aggr = Q;          // Q dead after edge pass 1... kept live through edge1; aggr reuses Q after
    // bf16 weight planes live in dead regions:
    //   qkv planes in ssum (consumed by k_mm_qkv BEFORE ssum memset)
    //   out planes in exp_ (written AFTER k_aggr, when exp_ is dead)
    ushort* Pq = (ushort*)ssum;   // 3 * 32768 ushorts = 192 KB  (<< N*8 floats)
    ushort* Po = (ushort*)exp_;   // 192 KB  (<< E*8 floats)

    const int nbm  = (N + BM - 1) / BM;
    const int nbsc = (N + SCAN_CHUNK - 1) / SCAN_CHUNK;   // scan blocks (<=256)

    // --- weight prep + ea (before memsets; Pq aliases ssum) ---
    k_prep3<<<dim3(128, 3), 128, 0, stream>>>(qW, kW, vW, Pq);
    k_ea<<<1, 128, 0, stream>>>(nt, et, mW1, mb1, m_g, m_b, m_m, m_v, mW2, mb2,
                                qW, qb, kW, kb, eaq, eak);
    k_mm_qkv<<<dim3(nbm, 3), 512, 0, stream>>>(x, Pq, eaq, eak, vb, Q, K, V, N);

    // planes consumed -> now zero ssum/deg (stream-ordered)
    hipMemsetAsync(ssum, 0, (size_t)N * 8 * sizeof(float), stream);
    hipMemsetAsync(deg, 0, (size_t)N * sizeof(int), stream);

    // CSR build (independent of Q/K/V values)
    k_hist<<<(E + 255) / 256, 256, 0, stream>>>(ei, deg, E);
    k_scan_partial<<<nbsc, 256, 0, stream>>>(deg, part, N);
    k_scan_top<<<1, 256, 0, stream>>>(part, nbsc);
    k_scan_final<<<nbsc, 256, 0, stream>>>(deg, part, row_start, cursor, N);
    k_scatter<<<(E + 255) / 256, 256, 0, stream>>>(ei, cursor, esrc, E);

    // edge pass 1 in CSR order: K resident per node, streaming exp writes
    k_edge1csr<<<(N + 3) / 4, 256, 0, stream>>>(esrc, row_start, deg, Q, K, exp_, ssum, N);
    k_vscale<<<(N * 32 + 255) / 256, 256, 0, stream>>>(V, ssum, N);
    k_aggr<<<(N + 3) / 4, 256, 0, stream>>>(esrc, row_start, deg, V, exp_, aggr, N);

    // --- fused output chain via MFMA (exp_ dead now; Po aliases it) ---
    k_prep_out<<<dim3(128, 3), 128, 0, stream>>>(resW, oW1, oW2, Po);
    k_out2<<<nbm, 1024, 0, stream>>>(x, Po, aggr, ob1, o_m, o_v, o_g, o_b, ob2, out, N);
}